// Round 1
// baseline (2074.053 us; speedup 1.0000x reference)
//
#include <hip/hip_runtime.h>
#include <hip/hip_bf16.h>

// STU forward for MI355X. R1: correctness-first, all heavy math as bf16 MFMA GEMMs.
// Sizes: B=2, L=1024, K=24, D=512, K_U=3, K_Y=2, USE_HANKEL_L=false.

typedef unsigned short u16;
typedef __attribute__((ext_vector_type(8))) short  vshort8;   // 8 bf16 (4 VGPR) MFMA frag
typedef __attribute__((ext_vector_type(4))) short  vshort4;
typedef __attribute__((ext_vector_type(4))) float  f32x4;
typedef __attribute__((ext_vector_type(4))) unsigned int vuint4;

__device__ __forceinline__ u16 f2b(float x) {
  __hip_bfloat16 h = __float2bfloat16(x);
  return __builtin_bit_cast(u16, h);
}
__device__ __forceinline__ float b2f(u16 x) {
  unsigned int u = ((unsigned int)x) << 16;
  return __builtin_bit_cast(float, u);
}

// ---------------------------------------------------------------------------
// Generic 128x128x(K) bf16 MFMA GEMM, C[m,n] = sum_k A[m,k]*B^T[n,k].
// Variants:
//  V0: GEMM1  A=X(2048x512) B=W1(Nx512), epi scatter -> A2T[(b,o,kh,s)] + Au
//  V1: GEMM2  A=Wc(1024x24576) B=A2T(per-b, ld 24576), triang skip, splitK2xb2 -> partials f32
//  V2: ZGEMM  A=gather(y_bf) (2048x16384), B=H-stack, triang kend, splitK4 -> zpart f32
//  V3: FIXUP  A=Abnd(64x1024), B=two-region(H,G), epi: out = z + acc
//  V4: DOUB   512x512x512 batched (z), C bf16, optional accumulate (ACCF)
// ---------------------------------------------------------------------------
struct GA {
  const u16* A; const u16* B; const u16* B2;
  float* Cf; u16* Cb;
  const float* zbuf; float* out;
  u16* A2T; u16* Au;
  long sAz, sBz, sCz;
  int M, N, lda, ldb;
  int kbeg, kend, nsplit;
};

template<int V, int ACCF>
__global__ __launch_bounds__(256) void gk(GA a) {
  const int tid = threadIdx.x;
  const int bn = blockIdx.x, bm = blockIdx.y, bz = blockIdx.z;
  const int m0 = bm * 128, n0 = bn * 128;
  const u16* Ap = a.A;
  const u16* Bp = a.B;
  if (V == 1) Bp = a.B + (size_t)(bz >> 1) * a.sBz;
  if (V == 4) Ap = a.A + (size_t)bz * a.sAz;

  __shared__ u16 lA[4096], lB[4096];
  f32x4 acc[4][4];
#pragma unroll
  for (int i = 0; i < 4; i++)
#pragma unroll
    for (int j = 0; j < 4; j++) acc[i][j] = f32x4{0.f, 0.f, 0.f, 0.f};

  int kbeg = a.kbeg, kend = a.kend;
  if (V == 1) { kbeg = (bz & 1) * 12288; kend = kbeg + 12288; }
  if (V == 2) {
    int tile_kend = ((((m0 + 127) >> 6)) + 1) << 9;
    kbeg = bz * 4096;
    kend = bz * 4096 + 4096;
    if (kend > tile_kend) kend = tile_kend;
  }
  const int lane = tid & 63, wv = tid >> 6, wr = wv >> 1, wc = wv & 1;

  for (int k0 = kbeg; k0 < kend; k0 += 32) {
    if (V == 1) { if ((k0 & 1023) > m0 + 127) continue; }
    // ---- stage A and B tiles into frag-major LDS ----
#pragma unroll
    for (int it = 0; it < 2; ++it) {
      int q = tid + it * 256;
      int r = q >> 2, cq = q & 3;
      vuint4 v;
      if (V == 2) {
        int m = m0 + r; int jj = m >> 6, b = (m >> 5) & 1, c = m & 31;
        int k = k0 + cq * 8; int tau = k >> 9, p = k & 511;
        if (tau > jj) v = vuint4{0u, 0u, 0u, 0u};
        else v = *(const vuint4*)(Ap + ((size_t)(b * 1024 + c * 32 + jj - tau)) * 512 + p);
      } else {
        int m = m0 + r;
        if (m < a.M) v = *(const vuint4*)(Ap + (size_t)m * a.lda + k0 + cq * 8);
        else v = vuint4{0u, 0u, 0u, 0u};
      }
      *(vuint4*)(&lA[(((r >> 4) * 4 + cq) * 16 + (r & 15)) * 8]) = v;

      int n = n0 + r;
      vuint4 w;
      if (V == 2) {
        int k = k0 + cq * 8; int tau = k >> 9, p = k & 511;
        w = *(const vuint4*)(Bp + (size_t)tau * 262144 + (size_t)n * 512 + p);
      } else if (V == 3) {
        int jj = n >> 9, o = n & 511; int k = k0 + cq * 8;
        const u16* src = (k < 512)
            ? (a.B  + (size_t)(jj + 1) * 262144 + (size_t)o * 512 + k)
            : (a.B2 + (size_t)jj * 262144 + (size_t)o * 512 + (k - 512));
        w = *(const vuint4*)src;
      } else {
        w = *(const vuint4*)(Bp + (size_t)n * a.ldb + k0 + cq * 8);
      }
      *(vuint4*)(&lB[(((r >> 4) * 4 + cq) * 16 + (r & 15)) * 8]) = w;
    }
    __syncthreads();
    vshort8 af[4], bf_[4];
#pragma unroll
    for (int s = 0; s < 4; s++) {
      af[s]  = *(const vshort8*)&lA[(((wr * 4 + s) * 4 + (lane >> 4)) * 16 + (lane & 15)) * 8];
      bf_[s] = *(const vshort8*)&lB[(((wc * 4 + s) * 4 + (lane >> 4)) * 16 + (lane & 15)) * 8];
    }
#pragma unroll
    for (int i = 0; i < 4; i++)
#pragma unroll
      for (int j = 0; j < 4; j++)
        acc[i][j] = __builtin_amdgcn_mfma_f32_16x16x32_bf16(af[i], bf_[j], acc[i][j], 0, 0, 0);
    __syncthreads();
  }

  // ---- epilogue ----
#pragma unroll
  for (int i = 0; i < 4; i++) {
    int em = m0 + wr * 64 + i * 16 + ((lane >> 4) << 2);
#pragma unroll
    for (int j = 0; j < 4; j++) {
      int n = n0 + wc * 64 + j * 16 + (lane & 15);
      f32x4 v = acc[i][j];
      if (V == 0) {
        int b = em >> 10, s = em & 1023;
        if (n < a.nsplit) {
          int kh = n >> 9, o = n & 511;
          vshort4 pk = { (short)f2b(v[0]), (short)f2b(v[1]), (short)f2b(v[2]), (short)f2b(v[3]) };
          *(vshort4*)(&a.A2T[((size_t)(b * 512 + o)) * 24576 + (size_t)kh * 1024 + s]) = pk;
        } else {
          int jj = (n - 12288) >> 9, o = n & 511;
#pragma unroll
          for (int t = 0; t < 4; t++)
            a.Au[(((size_t)(b * 3 + jj)) * 1024 + (s + t)) * 512 + o] = f2b(v[t]);
        }
      } else if (V == 1 || V == 2) {
        float* C = a.Cf + (size_t)bz * a.sCz;
#pragma unroll
        for (int t = 0; t < 4; t++) C[(size_t)(em + t) * 512 + n] = v[t];
      } else if (V == 3) {
        int jj = n >> 9, oo = n & 511;
#pragma unroll
        for (int t = 0; t < 4; t++) {
          int m = em + t;
          if (m < a.M) {
            int b = m >> 5, c = m & 31;
            float zv = a.zbuf[((size_t)(jj * 64 + m)) * 512 + oo];
            a.out[(size_t)b * 524288 + (size_t)(c * 32 + jj) * 512 + oo] = v[t] + zv;
          }
        }
      } else { // V4
        u16* C = a.Cb + (size_t)bz * a.sCz;
#pragma unroll
        for (int t = 0; t < 4; t++) {
          size_t off = (size_t)(em + t) * 512 + n;
          float x = v[t];
          if (ACCF) x += b2f(C[off]);
          C[off] = f2b(x);
        }
      }
    }
  }
}

// ---------------------------------------------------------------------------
// Elementwise / prep kernels
// ---------------------------------------------------------------------------
__global__ void k_prep_X(const float* __restrict__ u, u16* __restrict__ X, int n) {
  int i = blockIdx.x * 256 + threadIdx.x;
  if (i < n) X[i] = f2b(u[i]);
}

// phis[tau*48 + kf]: kf<24 -> phi_s[tau,kf] ; kf>=24 -> phi_s[tau,kf-24]*(-1)^tau
__global__ void k_prep_phis(const float* __restrict__ phi, const float* __restrict__ sigma,
                            float* __restrict__ phis) {
  int i = blockIdx.x * 256 + threadIdx.x;
  if (i >= 1024 * 48) return;
  int tau = i / 48, kf = i % 48, k = (kf >= 24) ? kf - 24 : kf;
  float v = phi[tau * 24 + k] * powf(sigma[k], 0.25f);
  if (kf >= 24 && (tau & 1)) v = -v;
  phis[i] = v;
}

__global__ void k_prep_W1(const float* __restrict__ Mp, const float* __restrict__ Mm,
                          const float* __restrict__ Mu, u16* __restrict__ W1, int h, int total) {
  int i = blockIdx.x * 256 + threadIdx.x;
  if (i >= total) return;
  float v;
  if (h == 0) v = (i < 12288 * 512) ? Mp[i] : Mu[i - 12288 * 512];
  else        v = Mm[i];
  W1[i] = f2b(v);
}

// Wc_h[t][kh*1024+s] = (t-s>=0) ? phis[(t-s)*48 + h*24 + kh] : 0
__global__ void k_prep_Wc(const float* __restrict__ phis, u16* __restrict__ Wc, int h) {
  int r = blockIdx.x * 256 + threadIdx.x;   // [0,24576)
  int t = blockIdx.y;                       // [0,1024)
  int kh = r >> 10, s = r & 1023;
  int tau = t - s;
  float v = (tau >= 0) ? phis[tau * 48 + h * 24 + kh] : 0.f;
  Wc[(size_t)t * 24576 + r] = f2b(v);
}

__global__ void k_initH(const float* __restrict__ my, u16* __restrict__ H, u16* __restrict__ G,
                        u16* __restrict__ HT, u16* __restrict__ M2T) {
  int i = blockIdx.x * 256 + threadIdx.x;
  if (i >= 262144) return;
  int o = i >> 9, p = i & 511;
  u16 id = (o == p) ? (u16)0x3F80 : (u16)0;
  float m1 = my[i];
  float m2 = my[262144 + i];
  H[i] = id;                                 // H0 = I
  HT[i] = id;                                // HT0 = I
  H[262144 + i] = f2b(m1);                   // H1 = M1
  G[i] = f2b(m2);                            // G0 = M2
  HT[262144 + (p << 9) + o] = f2b(m1);       // HT1 = M1^T
  M2T[(p << 9) + o] = f2b(m2);               // M2^T
}

__global__ void k_transpose(const u16* __restrict__ src, u16* __restrict__ dst) {
  size_t base = (size_t)blockIdx.z * 262144;
  int i = blockIdx.x * 256 + threadIdx.x;
  int o = i >> 9, p = i & 511;
  dst[base + ((size_t)p << 9) + o] = src[base + i];
}

// y[b,t,o] = sum_j Au[b,j,t-j,o] + (t>=2 ? spec[b,t-2,o] : 0) -> bf16
__global__ void k_combine(const float* __restrict__ parts, const u16* __restrict__ Au,
                          u16* __restrict__ ybf) {
  int i = blockIdx.x * 256 + threadIdx.x;
  if (i >= 1048576) return;
  int b = i >> 19, rest = i & 524287, t = rest >> 9, o = rest & 511;
  float y = 0.f;
#pragma unroll
  for (int j = 0; j < 3; j++)
    if (t >= j) y += b2f(Au[(((size_t)(b * 3 + j)) * 1024 + (t - j)) * 512 + o]);
  if (t >= 2) {
    size_t e = (size_t)(t - 2) * 512 + o;
    y += parts[(size_t)(0 + b * 2 + 0) * 524288 + e] + parts[(size_t)(0 + b * 2 + 1) * 524288 + e]
       + parts[(size_t)(4 + b * 2 + 0) * 524288 + e] + parts[(size_t)(4 + b * 2 + 1) * 524288 + e];
  }
  ybf[i] = f2b(y);
}

__global__ void k_zreduce(const float* __restrict__ zp, float* __restrict__ z) {
  int i = blockIdx.x * 256 + threadIdx.x;
  if (i < 1048576)
    z[i] = zp[i] + zp[i + 1048576] + zp[i + 2097152] + zp[i + 3145728];
}

// one chunk step: bnd{1,2}[c+1] = z rows {31,30} of chunk c + H{32,31} bnd1[c] + G{31,30} bnd2[c]
__global__ void k_boundary(const u16* __restrict__ H, const u16* __restrict__ G,
                           const float* __restrict__ z, float* __restrict__ bnd1,
                           float* __restrict__ bnd2, int c) {
  int idx = blockIdx.x * 256 + threadIdx.x;   // 2048
  int r2 = idx >> 10, b = (idx >> 9) & 1, o = idx & 511;
  int jrow = (r2 == 0) ? 31 : 30;
  const u16* Hm = H + (size_t)(jrow + 1) * 262144 + (size_t)o * 512;
  const u16* Gm = G + (size_t)jrow * 262144 + (size_t)o * 512;
  const float* b1 = bnd1 + (size_t)(c * 2 + b) * 512;
  const float* b2 = bnd2 + (size_t)(c * 2 + b) * 512;
  float s = z[((size_t)(jrow * 64 + b * 32 + c)) * 512 + o];
  for (int p = 0; p < 512; ++p)
    s += b2f(Hm[p]) * b1[p] + b2f(Gm[p]) * b2[p];
  float* dst = (r2 == 0) ? bnd1 : bnd2;
  dst[(size_t)((c + 1) * 2 + b) * 512 + o] = s;
}

__global__ void k_abnd(const float* __restrict__ bnd1, const float* __restrict__ bnd2,
                       u16* __restrict__ Abnd) {
  int i = blockIdx.x * 256 + threadIdx.x;   // 65536
  int m = i >> 10, k = i & 1023, b = m >> 5, c = m & 31;
  float v = (k < 512) ? bnd1[(size_t)(c * 2 + b) * 512 + k]
                      : bnd2[(size_t)(c * 2 + b) * 512 + (k - 512)];
  Abnd[i] = f2b(v);
}

// ---------------------------------------------------------------------------
extern "C" void kernel_launch(void* const* d_in, const int* in_sizes, int n_in,
                              void* d_out, int out_size, void* d_ws, size_t ws_size,
                              hipStream_t stream) {
  const float* u     = (const float*)d_in[0];
  const float* Mu    = (const float*)d_in[1];
  const float* Mp    = (const float*)d_in[2];
  const float* Mm    = (const float*)d_in[3];
  const float* my    = (const float*)d_in[4];
  const float* sigma = (const float*)d_in[5];
  const float* phi   = (const float*)d_in[6];
  float* out = (float*)d_out;

  char* ws = (char*)d_ws;
  size_t off = 0;
  auto alc = [&](size_t b) { size_t p = off; off = (off + b + 255) & ~(size_t)255; return p; };
  u16*  X     = (u16*)(ws + alc(2097152));    // u bf16 (2048x512)
  u16*  W1    = (u16*)(ws + alc(14155776));   // up to 13824x512
  u16*  A2T   = (u16*)(ws + alc(50331648));   // (b,o,kh,s) per half
  u16*  Wc    = (u16*)(ws + alc(50331648));   // 1024x24576 per half
  u16*  Au    = (u16*)(ws + alc(6291456));    // (b,3,1024,512)
  float* parts = (float*)(ws + alc(16777216)); // 8 slots GEMM2 / 4 slots ZGEMM
  u16*  ybf   = (u16*)(ws + alc(2097152));
  u16*  Hb    = (u16*)(ws + alc(17301504));   // H_0..H_32
  u16*  Gb    = (u16*)(ws + alc(17301504));   // G_0..G_32
  u16*  HTb   = (u16*)(ws + alc(17301504));
  u16*  M2T   = (u16*)(ws + alc(524288));
  float* phis = (float*)(ws + alc(196608));
  float* zf   = (float*)(ws + alc(4194304));
  float* bnd1 = (float*)(ws + alc(135168));
  float* bnd2 = (float*)(ws + alc(135168));
  u16*  Abnd  = (u16*)(ws + alc(131072));
  if (off > ws_size) return;  // workspace too small -> visible failure

  // --- prep ---
  k_prep_X<<<dim3(4096), 256, 0, stream>>>(u, X, 1048576);
  k_prep_phis<<<dim3(192), 256, 0, stream>>>(phi, sigma, phis);
  k_initH<<<dim3(1024), 256, 0, stream>>>(my, Hb, Gb, HTb, M2T);

  // G1 = H1 @ M2
  {
    GA g{}; g.A = Hb + 262144; g.B = M2T; g.Cb = Gb + 262144;
    g.M = 512; g.N = 512; g.lda = 512; g.ldb = 512; g.kbeg = 0; g.kend = 512;
    gk<4, 0><<<dim3(4, 4, 1), 256, 0, stream>>>(g);
  }
  // doubling levels: count 2->3->5->9->17->33
  {
    const int cs[5] = {2, 3, 5, 9, 17};
    for (int li = 0; li < 5; ++li) {
      int c = cs[li], cnt = c - 1;
      GA s{}; s.M = 512; s.N = 512; s.lda = 512; s.ldb = 512; s.kbeg = 0; s.kend = 512;
      s.A = Hb + 262144; s.sAz = 262144;
      s.B = HTb + (size_t)(c - 1) * 262144;
      s.Cb = Hb + (size_t)c * 262144; s.sCz = 262144;
      gk<4, 0><<<dim3(4, 4, cnt), 256, 0, stream>>>(s);       // H_{c+z}  = H_{z+1} @ H_{c-1}
      s.A = Gb; s.B = HTb + (size_t)(c - 2) * 262144;
      gk<4, 1><<<dim3(4, 4, cnt), 256, 0, stream>>>(s);       // H_{c+z} += G_z @ H_{c-2}
      GA t{}; t.M = 512; t.N = 512; t.lda = 512; t.ldb = 512; t.kbeg = 0; t.kend = 512;
      t.A = Hb + (size_t)c * 262144; t.sAz = 262144; t.B = M2T;
      t.Cb = Gb + (size_t)c * 262144; t.sCz = 262144;
      gk<4, 0><<<dim3(4, 4, cnt), 256, 0, stream>>>(t);       // G_{c+z} = H_{c+z} @ M2
      k_transpose<<<dim3(1024, 1, cnt), 256, 0, stream>>>(Hb + (size_t)c * 262144,
                                                          HTb + (size_t)c * 262144);
    }
  }

  // --- spectral + ar_u, two k-halves ---
  for (int h = 0; h < 2; ++h) {
    int N1 = h ? 12288 : 13824;
    k_prep_W1<<<dim3((N1 * 512) / 256), 256, 0, stream>>>(Mp, Mm, Mu, W1, h, N1 * 512);
    k_prep_Wc<<<dim3(96, 1024), 256, 0, stream>>>(phis, Wc, h);
    GA g1{}; g1.A = X; g1.B = W1; g1.A2T = A2T; g1.Au = Au;
    g1.M = 2048; g1.N = N1; g1.lda = 512; g1.ldb = 512; g1.kbeg = 0; g1.kend = 512;
    g1.nsplit = h ? 24576 : 12288;
    gk<0, 0><<<dim3(N1 / 128, 16, 1), 256, 0, stream>>>(g1);
    GA g2{}; g2.A = Wc; g2.lda = 24576; g2.B = A2T; g2.ldb = 24576; g2.sBz = 12582912;
    g2.Cf = parts + (size_t)h * 2097152; g2.sCz = 524288; g2.M = 1024; g2.N = 512;
    gk<1, 0><<<dim3(4, 8, 4), 256, 0, stream>>>(g2);
  }
  k_combine<<<dim3(4096), 256, 0, stream>>>(parts, Au, ybf);

  // --- ar_y: z = Tri(H) y (chunks of 32) ---
  {
    GA gz{}; gz.A = ybf; gz.B = Hb; gz.Cf = parts; gz.sCz = 1048576;
    gz.M = 2048; gz.N = 512;
    gk<2, 0><<<dim3(4, 16, 4), 256, 0, stream>>>(gz);
  }
  k_zreduce<<<dim3(4096), 256, 0, stream>>>(parts, zf);

  hipMemsetAsync(bnd1, 0, 270336, stream);  // bnd1+bnd2 contiguous
  for (int c = 0; c < 31; ++c)
    k_boundary<<<dim3(8), 256, 0, stream>>>(Hb, Gb, zf, bnd1, bnd2, c);
  k_abnd<<<dim3(256), 256, 0, stream>>>(bnd1, bnd2, Abnd);

  {
    GA gf{}; gf.A = Abnd; gf.lda = 1024; gf.B = Hb; gf.B2 = Gb; gf.zbuf = zf; gf.out = out;
    gf.M = 64; gf.N = 16384; gf.kbeg = 0; gf.kend = 1024;
    gk<3, 0><<<dim3(128, 1, 1), 256, 0, stream>>>(gf);
  }
}

// Round 3
// 801.802 us; speedup vs baseline: 2.5867x; 2.5867x over previous
//
#include <hip/hip_runtime.h>
#include <hip/hip_bf16.h>

// STU forward, R3: R2 with the V5 A-load m0 bug fixed.
// Sizes: B=2, L=1024, K=24(x2 branches), D=512, K_U=3, K_Y=2.

typedef unsigned short u16;
typedef __attribute__((ext_vector_type(8))) short  vshort8;
typedef __attribute__((ext_vector_type(4))) short  vshort4;
typedef __attribute__((ext_vector_type(4))) float  f32x4;
typedef __attribute__((ext_vector_type(4))) unsigned int vuint4;

__device__ __forceinline__ u16 f2b(float x) {
  __hip_bfloat16 h = __float2bfloat16(x);
  return __builtin_bit_cast(u16, h);
}
__device__ __forceinline__ float b2f(u16 x) {
  unsigned int u = ((unsigned int)x) << 16;
  return __builtin_bit_cast(float, u);
}

// ---------------------------------------------------------------------------
// Shared 128x128 MFMA GEMM template. C[m,n] = sum_k A[m,k]*Bmat[n,k].
//  V0 GEMM1: A=X(2048x512) B=W1(26112x512) -> scatter A2T + Au
//  V1 CONV : A=Wtoep strips, B=A2T, z=(j s-block, b), triangular -> parts f32
//  V2 ZGEMM: A=gather(ybf), B=Top (H_tau blocks), splitK over tau -> zparts f32
//  V3 FIXUP: A=Abnd(64x1024), B=Top[j+1] rows -> out = acc + zf
//  V5 SGEMM: A=Top[1+bz] (512x1024), B=STc -> Top[c+1+bz] bf16 (batched)
// ---------------------------------------------------------------------------
struct GB {
  const u16* A; const u16* B;
  float* Cf; u16* Cb;
  const float* zf; float* out;
  u16* A2T; u16* Au;
  int M, N;
};

template<int V>
__global__ __launch_bounds__(256) void g2(GB a) {
  const int tid = threadIdx.x;
  const int bn = blockIdx.x, bm = blockIdx.y, bz = blockIdx.z;
  const int m0 = bm * 128, n0 = bn * 128;
  __shared__ u16 lA[4096], lB[4096];
  f32x4 acc[4][4];
#pragma unroll
  for (int i = 0; i < 4; i++)
#pragma unroll
    for (int j = 0; j < 4; j++) acc[i][j] = f32x4{0.f, 0.f, 0.f, 0.f};

  int kbeg = 0, kend = 0;
  int cj = 0, cb = 0, cd = 0;
  if (V == 0) kend = 512;
  if (V == 1) { cj = bz & 7; cb = bz >> 3; cd = bm - cj; kend = (cj <= bm) ? 6144 : 0; }
  if (V == 2) {
    int jmax = (m0 >> 6) + 1;
    kbeg = bz * 2048;
    kend = kbeg + 2048;
    int tk = (jmax + 1) * 512;
    if (kend > tk) kend = tk;
    if (kend < kbeg) kend = kbeg;
  }
  if (V == 3) kend = 1024;
  if (V == 5) kend = 1024;

  const int lane = tid & 63, wv = tid >> 6, wr = wv >> 1, wc = wv & 1;
  const u16* Ap = a.A;
  if (V == 5) Ap = a.A + (size_t)bz * 524288;

  for (int k0 = kbeg; k0 < kend; k0 += 32) {
#pragma unroll
    for (int it = 0; it < 2; ++it) {
      int q = tid + it * 256;
      int r = q >> 2, cq = q & 3;
      int kk = k0 + cq * 8;
      vuint4 v;
      if (V == 0) {
        v = *(const vuint4*)(Ap + (size_t)(m0 + r) * 512 + kk);
      } else if (V == 1) {
        v = *(const vuint4*)(Ap + (size_t)cd * 786432 + (size_t)r * 6144 + kk);
      } else if (V == 2) {
        int m = m0 + r, j = m >> 6, b = (m >> 5) & 1, c = m & 31;
        int tau = kk >> 9, p = kk & 511;
        if (tau > j) v = vuint4{0u, 0u, 0u, 0u};
        else v = *(const vuint4*)(Ap + (size_t)(b * 1024 + c * 32 + j - tau) * 512 + p);
      } else if (V == 3) {
        int m = m0 + r;
        if (m < a.M) v = *(const vuint4*)(Ap + (size_t)m * 1024 + kk);
        else v = vuint4{0u, 0u, 0u, 0u};
      } else { // V5
        v = *(const vuint4*)(Ap + (size_t)(m0 + r) * 1024 + kk);
      }
      *(vuint4*)(&lA[(((r >> 4) * 4 + cq) * 16 + (r & 15)) * 8]) = v;

      int n = n0 + r;
      vuint4 w;
      if (V == 0) {
        w = *(const vuint4*)(a.B + (size_t)n * 512 + kk);
      } else if (V == 1) {
        int kh = kk >> 7, sp = kk & 127;
        w = *(const vuint4*)(a.B + (size_t)(cb * 512 + n) * 49152 + kh * 1024 + cj * 128 + sp);
      } else if (V == 2) {
        int tau = kk >> 9, p = kk & 511;
        w = *(const vuint4*)(a.B + (size_t)tau * 524288 + (size_t)n * 1024 + p);
      } else if (V == 3) {
        int jn = n >> 9, o = n & 511;
        w = *(const vuint4*)(a.B + (size_t)(jn + 1) * 524288 + (size_t)o * 1024 + kk);
      } else { // V5
        w = *(const vuint4*)(a.B + (size_t)n * 1024 + kk);
      }
      *(vuint4*)(&lB[(((r >> 4) * 4 + cq) * 16 + (r & 15)) * 8]) = w;
    }
    __syncthreads();
    vshort8 af[4], bf_[4];
#pragma unroll
    for (int s = 0; s < 4; s++) {
      af[s]  = *(const vshort8*)&lA[(((wr * 4 + s) * 4 + (lane >> 4)) * 16 + (lane & 15)) * 8];
      bf_[s] = *(const vshort8*)&lB[(((wc * 4 + s) * 4 + (lane >> 4)) * 16 + (lane & 15)) * 8];
    }
#pragma unroll
    for (int i = 0; i < 4; i++)
#pragma unroll
      for (int j = 0; j < 4; j++)
        acc[i][j] = __builtin_amdgcn_mfma_f32_16x16x32_bf16(af[i], bf_[j], acc[i][j], 0, 0, 0);
    __syncthreads();
  }

  // epilogue
#pragma unroll
  for (int i = 0; i < 4; i++) {
    int em = m0 + wr * 64 + i * 16 + ((lane >> 4) << 2);
#pragma unroll
    for (int j = 0; j < 4; j++) {
      int n = n0 + wc * 64 + j * 16 + (lane & 15);
      f32x4 v = acc[i][j];
      if (V == 0) {
        int b = em >> 10, s = em & 1023;
        if (n < 24576) {
          int kh = n >> 9, o = n & 511;
          vshort4 pk = { (short)f2b(v[0]), (short)f2b(v[1]), (short)f2b(v[2]), (short)f2b(v[3]) };
          *(vshort4*)(&a.A2T[(size_t)(b * 512 + o) * 49152 + (size_t)kh * 1024 + s]) = pk;
        } else {
          int jj = (n - 24576) >> 9, o = n & 511;
#pragma unroll
          for (int t = 0; t < 4; t++)
            a.Au[((size_t)(b * 3 + jj) * 1024 + (s + t)) * 512 + o] = f2b(v[t]);
        }
      } else if (V == 1) {
        float* C = a.Cf + (size_t)bz * 524288;
#pragma unroll
        for (int t = 0; t < 4; t++) C[(size_t)(em + t) * 512 + n] = v[t];
      } else if (V == 2) {
        float* C = a.Cf + (size_t)bz * 1048576;
#pragma unroll
        for (int t = 0; t < 4; t++) C[(size_t)(em + t) * 512 + n] = v[t];
      } else if (V == 3) {
        int jj = n >> 9, oo = n & 511;
#pragma unroll
        for (int t = 0; t < 4; t++) {
          int m = em + t;
          if (m < a.M) {
            int b = m >> 5, c = m & 31;
            float zv = a.zf[(size_t)(jj * 64 + b * 32 + c) * 512 + oo];
            a.out[(size_t)b * 524288 + (size_t)(c * 32 + jj) * 512 + oo] = v[t] + zv;
          }
        }
      } else { // V5
        u16* C = a.Cb + (size_t)bz * 524288;
#pragma unroll
        for (int t = 0; t < 4; t++) C[(size_t)(em + t) * 1024 + n] = f2b(v[t]);
      }
    }
  }
}

// ---------------------------------------------------------------------------
// prep / glue kernels
// ---------------------------------------------------------------------------
__global__ void k_prep_X(const float* __restrict__ u, u16* __restrict__ X, int n) {
  int i = blockIdx.x * 256 + threadIdx.x;
  if (i < n) X[i] = f2b(u[i]);
}

__global__ void k_prep_phis(const float* __restrict__ phi, const float* __restrict__ sigma,
                            float* __restrict__ phis) {
  int i = blockIdx.x * 256 + threadIdx.x;
  if (i >= 1024 * 48) return;
  int tau = i / 48, kf = i % 48, k = (kf >= 24) ? kf - 24 : kf;
  float v = phi[tau * 24 + k] * powf(sigma[k], 0.25f);
  if (kf >= 24 && (tau & 1)) v = -v;
  phis[i] = v;
}

__global__ void k_prep_W1(const float* __restrict__ Mp, const float* __restrict__ Mm,
                          const float* __restrict__ Mu, u16* __restrict__ W1) {
  int i = blockIdx.x * 256 + threadIdx.x;
  if (i >= 13369344) return;
  float v;
  if (i < 6291456) v = Mp[i];
  else if (i < 12582912) v = Mm[i - 6291456];
  else v = Mu[i - 12582912];
  W1[i] = f2b(v);
}

// Wtoep[d][t'][kh*128+s'] = phis[(d*128+t'-s')*48 + kh] (0 if tau<0)
__global__ void k_prep_Wtoep(const float* __restrict__ phis, u16* __restrict__ W) {
  int i = blockIdx.x * 256 + threadIdx.x;
  if (i >= 6291456) return;
  int kap = i % 6144, row = i / 6144;
  int tp = row & 127, d = row >> 7;
  int kh = kap >> 7, sp = kap & 127;
  int tau = d * 128 + tp - sp;
  W[i] = (tau >= 0 && tau < 1024) ? f2b(phis[tau * 48 + kh]) : (u16)0;
}

// Top[0]=[I|0], Top[1]=[M1|M2]
__global__ void k_initTop(const float* __restrict__ my, u16* __restrict__ Top) {
  int i = blockIdx.x * 256 + threadIdx.x;
  if (i >= 1048576) return;
  int mat = i >> 19, rem = i & 524287, o = rem >> 10, k = rem & 1023;
  u16 v;
  if (mat == 0) v = (k == o) ? (u16)0x3F80 : (u16)0;
  else v = (k < 512) ? f2b(my[o * 512 + k]) : f2b(my[262144 + o * 512 + (k - 512)]);
  Top[i] = v;
}

// STc[n][k] = S^c[k][n];  S^c = [Top[c]; Top[c-1]]  (tiled transpose)
__global__ __launch_bounds__(256) void k_transT(const u16* __restrict__ Top,
                                                u16* __restrict__ STc, int c) {
  __shared__ u16 tile[64][72];
  int tx = blockIdx.x, ty = blockIdx.y;  // n-tile, k-tile
  int tid = threadIdx.x;
  int r = tid >> 2, seg = tid & 3;
  int k = ty * 64 + r;
  const u16* src = (k < 512) ? Top + (size_t)c * 524288 + (size_t)k * 1024 + tx * 64
                             : Top + (size_t)(c - 1) * 524288 + (size_t)(k - 512) * 1024 + tx * 64;
  *(vuint4*)&tile[r][seg * 16]     = *(const vuint4*)(src + seg * 16);
  *(vuint4*)&tile[r][seg * 16 + 8] = *(const vuint4*)(src + seg * 16 + 8);
  __syncthreads();
  int n = tx * 64 + r;
  u16 tmp[16];
#pragma unroll
  for (int j = 0; j < 16; j++) tmp[j] = tile[seg * 16 + j][r];
  *(vuint4*)&STc[(size_t)n * 1024 + ty * 64 + seg * 16]     = *(vuint4*)&tmp[0];
  *(vuint4*)&STc[(size_t)n * 1024 + ty * 64 + seg * 16 + 8] = *(vuint4*)&tmp[8];
}

// ybf[b,t,o] = sum_j Au[b,j,t-j,o] + (t>=2 ? sum_{j<8} parts[(b*8+j)][t-2][o] : 0)
__global__ void k_combine(const float* __restrict__ parts, const u16* __restrict__ Au,
                          u16* __restrict__ ybf) {
  int i = blockIdx.x * 256 + threadIdx.x;
  if (i >= 1048576) return;
  int b = i >> 19, rest = i & 524287, t = rest >> 9, o = rest & 511;
  float y = 0.f;
#pragma unroll
  for (int j = 0; j < 3; j++)
    if (t >= j) y += b2f(Au[((size_t)(b * 3 + j) * 1024 + (t - j)) * 512 + o]);
  if (t >= 2) {
    size_t e = (size_t)(t - 2) * 512 + o;
#pragma unroll
    for (int j = 0; j < 8; j++) y += parts[(size_t)(b * 8 + j) * 524288 + e];
  }
  ybf[i] = f2b(y);
}

__global__ void k_zreduce(const float* __restrict__ zp, float* __restrict__ z) {
  int i = blockIdx.x * 256 + threadIdx.x;
  if (i >= 1048576) return;
  float s = 0.f;
#pragma unroll
  for (int j = 0; j < 8; j++) s += zp[(size_t)j * 1048576 + i];
  z[i] = s;
}

// one boundary step: state_{c+1} = S^32 @ state_c + zb_c ; also emit Abnd rows
__global__ __launch_bounds__(256) void k_bnd(const u16* __restrict__ Top,
                                             const float* __restrict__ zf,
                                             float* __restrict__ bnd,
                                             u16* __restrict__ Abnd, int c) {
  __shared__ float st[2048];
  int tid = threadIdx.x;
  const float* s0 = bnd + (size_t)c * 2048;
  for (int j = tid; j < 2048; j += 256) st[j] = s0[j];
  __syncthreads();
  int q4 = blockIdx.x * 256 + tid;  // [0,8192)
  int q = q4 >> 2, quarter = q4 & 3;
  int b = q >> 10, kk = q & 1023;
  const u16* row = (kk < 512) ? Top + (size_t)32 * 524288 + (size_t)kk * 1024
                              : Top + (size_t)31 * 524288 + (size_t)(kk - 512) * 1024;
  const float* stb = st + b * 1024 + quarter * 256;
  const u16* rp = row + quarter * 256;
  float sum = 0.f;
  for (int t = 0; t < 32; ++t) {
    vuint4 v = *(const vuint4*)(rp + t * 8);
    const unsigned int* vu = (const unsigned int*)&v;
#pragma unroll
    for (int e = 0; e < 4; ++e) {
      unsigned int pw = vu[e];
      float lo = __builtin_bit_cast(float, (pw & 0xffffu) << 16);
      float hi = __builtin_bit_cast(float, pw & 0xffff0000u);
      sum += lo * stb[t * 8 + e * 2] + hi * stb[t * 8 + e * 2 + 1];
    }
  }
  sum += __shfl_xor(sum, 1);
  sum += __shfl_xor(sum, 2);
  if (quarter == 0) {
    int jrow = (kk < 512) ? 31 : 30, o = kk & 511;
    float s = sum + zf[(size_t)(jrow * 64 + b * 32 + c) * 512 + o];
    bnd[(size_t)(c + 1) * 2048 + b * 1024 + kk] = s;
    Abnd[(size_t)(b * 32 + c + 1) * 1024 + kk] = f2b(s);
  }
}

// ---------------------------------------------------------------------------
extern "C" void kernel_launch(void* const* d_in, const int* in_sizes, int n_in,
                              void* d_out, int out_size, void* d_ws, size_t ws_size,
                              hipStream_t stream) {
  const float* u     = (const float*)d_in[0];
  const float* Mu    = (const float*)d_in[1];
  const float* Mp    = (const float*)d_in[2];
  const float* Mm    = (const float*)d_in[3];
  const float* my    = (const float*)d_in[4];
  const float* sigma = (const float*)d_in[5];
  const float* phi   = (const float*)d_in[6];
  float* out = (float*)d_out;

  char* ws = (char*)d_ws;
  size_t off = 0;
  auto alc = [&](size_t b) { size_t p = off; off = (off + b + 255) & ~(size_t)255; return p; };
  u16*  X     = (u16*)(ws + alc(2097152));
  u16*  A2T   = (u16*)(ws + alc(100663296));   // (b,o)[48 kh][1024 s]
  u16*  W1    = (u16*)(ws + alc(26738688));    // 26112x512
  u16*  Wtoep = (u16*)(ws + alc(12582912));    // 8 d x 128 x 6144
  u16*  Au    = (u16*)(ws + alc(6291456));
  float* parts = (float*)(ws + alc(33554432)); // 16 conv slots / 8 zgemm slots
  float* phis = (float*)(ws + alc(196608));
  float* bnd  = (float*)(ws + alc(262144));    // 32 states x 2b x 1024 f32
  u16*  Abnd  = (u16*)(ws + alc(131072));
  if (off > ws_size) return;
  // aliases (lifetime-disjoint):
  u16*  Top   = W1;                            // 33 x 512x1024 bf16 (after conv; spills into dead Wtoep)
  u16*  STc   = W1 + 17301504;                 // 1024x1024 bf16 scratch (dead Wtoep region)
  u16*  ybf   = A2T;                           // after conv
  float* zf   = (float*)((char*)A2T + 4194304);
  float* zparts = parts;

  // prep
  k_prep_X<<<dim3(4096), 256, 0, stream>>>(u, X, 1048576);
  k_prep_phis<<<dim3(192), 256, 0, stream>>>(phi, sigma, phis);
  k_prep_W1<<<dim3(52224), 256, 0, stream>>>(Mp, Mm, Mu, W1);
  k_prep_Wtoep<<<dim3(24576), 256, 0, stream>>>(phis, Wtoep);

  // GEMM1: projections (spectral plus/minus + ar_u)
  {
    GB g{}; g.A = X; g.B = W1; g.A2T = A2T; g.Au = Au; g.M = 2048; g.N = 26112;
    g2<0><<<dim3(204, 16, 1), 256, 0, stream>>>(g);
  }
  // CONV: block-Toeplitz causal conv, splitK over (j,b)
  {
    GB g{}; g.A = Wtoep; g.B = A2T; g.Cf = parts; g.M = 1024; g.N = 512;
    g2<1><<<dim3(4, 8, 16), 256, 0, stream>>>(g);
  }
  k_combine<<<dim3(4096), 256, 0, stream>>>(parts, Au, ybf);

  // companion-power stack S^0..S^32 (top halves)
  k_initTop<<<dim3(4096), 256, 0, stream>>>(my, Top);
  {
    const int cs[5] = {1, 2, 4, 8, 16};
    for (int li = 0; li < 5; ++li) {
      int c = cs[li];
      k_transT<<<dim3(16, 16), 256, 0, stream>>>(Top, STc, c);
      GB s{}; s.A = Top + 524288; s.B = STc; s.Cb = Top + (size_t)(c + 1) * 524288;
      s.M = 512; s.N = 1024;
      g2<5><<<dim3(8, 4, c), 256, 0, stream>>>(s);
    }
  }

  // within-chunk solve: z = Tri(H) y, splitK over tau-blocks
  {
    GB g{}; g.A = ybf; g.B = Top; g.Cf = zparts; g.M = 2048; g.N = 512;
    g2<2><<<dim3(4, 16, 8), 256, 0, stream>>>(g);
  }
  k_zreduce<<<dim3(4096), 256, 0, stream>>>(zparts, zf);

  // boundary chain (31 steps) + Abnd emission
  hipMemsetAsync(bnd, 0, 8192, stream);
  hipMemsetAsync(Abnd, 0, 131072, stream);
  for (int c = 0; c < 31; ++c)
    k_bnd<<<dim3(32), 256, 0, stream>>>(Top, zf, bnd, Abnd, c);

  // fixup: out = z + [H_{j+1}|G_j] @ Abnd
  {
    GB g{}; g.A = Abnd; g.B = Top; g.zf = zf; g.out = out; g.M = 64; g.N = 16384;
    g2<3><<<dim3(128, 1, 1), 256, 0, stream>>>(g);
  }
}

// Round 4
// 779.098 us; speedup vs baseline: 2.6621x; 1.0291x over previous
//
#include <hip/hip_runtime.h>
#include <hip/hip_bf16.h>

// STU forward, R4: active-only split-K conv (576 blocks), 2-step-unrolled
// boundary chain (15 serial steps + batched odd fill).
// Sizes: B=2, L=1024, K=24(x2 branches), D=512, K_U=3, K_Y=2.

typedef unsigned short u16;
typedef __attribute__((ext_vector_type(8))) short  vshort8;
typedef __attribute__((ext_vector_type(4))) short  vshort4;
typedef __attribute__((ext_vector_type(4))) float  f32x4;
typedef __attribute__((ext_vector_type(4))) unsigned int vuint4;

__device__ __forceinline__ u16 f2b(float x) {
  __hip_bfloat16 h = __float2bfloat16(x);
  return __builtin_bit_cast(u16, h);
}
__device__ __forceinline__ float b2f(u16 x) {
  unsigned int u = ((unsigned int)x) << 16;
  return __builtin_bit_cast(float, u);
}

// ---------------------------------------------------------------------------
// Shared 128x128 MFMA GEMM template. C[m,n] = sum_k A[m,k]*Bmat[n,k].
//  V0 GEMM1: A=X(2048x512) B=W1(26112x512) -> scatter A2T + Au
//  V1 CONV : A=Wtoep strip (d=bm-cj), B=A2T, grid (36 tri, 4 bn, 4 cb*ch)
//  V2 ZGEMM: A=gather(ybf), B=Top (H_tau blocks), splitK over tau -> zparts
//  V3 FIXUP: A=Abnd(64x1024), B=Top[j+1] rows -> out = acc + zf
//  V5 SGEMM: A=Top[*+bz] (512x1024), B=STc -> Top[*+bz] bf16 (batched)
//  V6 UGEMM: A=Wm(64x1024), B=S32 rows -> ubuf = acc + w_{c+1} (f32)
//  V7 ODD  : A=Abnd even rows, B=S32 rows -> Abnd odd rows = acc + w_{2k}
// ---------------------------------------------------------------------------
struct GB {
  const u16* A; const u16* B;
  float* Cf; u16* Cb;
  const float* zf; float* out;
  u16* A2T; u16* Au;
  int M, N;
};

template<int V>
__global__ __launch_bounds__(256) void g2(GB a) {
  const int tid = threadIdx.x;
  int bn = blockIdx.x, bm = blockIdx.y;
  const int bz = blockIdx.z;
  int cj = 0, cb = 0, cd = 0, chh = 0;
  if (V == 1) {
    int p = blockIdx.x;
    bm = (int)((sqrtf(8.f * (float)p + 1.f) - 1.f) * 0.5f);
    cj = p - (bm * (bm + 1)) / 2;
    bn = blockIdx.y;
    cb = bz >> 1; chh = bz & 1; cd = bm - cj;
  }
  const int m0 = bm * 128, n0 = bn * 128;
  __shared__ u16 lA[4096], lB[4096];
  f32x4 acc[4][4];
#pragma unroll
  for (int i = 0; i < 4; i++)
#pragma unroll
    for (int j = 0; j < 4; j++) acc[i][j] = f32x4{0.f, 0.f, 0.f, 0.f};

  int kbeg = 0, kend = 0;
  if (V == 0) kend = 512;
  if (V == 1) { kbeg = chh * 3072; kend = kbeg + 3072; }
  if (V == 2) {
    int jmax = (m0 >> 6) + 1;
    kbeg = bz * 2048;
    kend = kbeg + 2048;
    int tk = (jmax + 1) * 512;
    if (kend > tk) kend = tk;
    if (kend < kbeg) kend = kbeg;
  }
  if (V == 3 || V == 5 || V == 6 || V == 7) kend = 1024;

  const int lane = tid & 63, wv = tid >> 6, wr = wv >> 1, wc = wv & 1;
  const u16* Ap = a.A;
  if (V == 5) Ap = a.A + (size_t)bz * 524288;

  for (int k0 = kbeg; k0 < kend; k0 += 32) {
#pragma unroll
    for (int it = 0; it < 2; ++it) {
      int q = tid + it * 256;
      int r = q >> 2, cq = q & 3;
      int kk = k0 + cq * 8;
      vuint4 v;
      if (V == 0) {
        v = *(const vuint4*)(Ap + (size_t)(m0 + r) * 512 + kk);
      } else if (V == 1) {
        v = *(const vuint4*)(Ap + (size_t)cd * 786432 + (size_t)r * 6144 + kk);
      } else if (V == 2) {
        int m = m0 + r, j = m >> 6, b = (m >> 5) & 1, c = m & 31;
        int tau = kk >> 9, p = kk & 511;
        if (tau > j) v = vuint4{0u, 0u, 0u, 0u};
        else v = *(const vuint4*)(Ap + (size_t)(b * 1024 + c * 32 + j - tau) * 512 + p);
      } else if (V == 3) {
        int m = m0 + r;
        if (m < a.M) v = *(const vuint4*)(Ap + (size_t)m * 1024 + kk);
        else v = vuint4{0u, 0u, 0u, 0u};
      } else if (V == 5) {
        v = *(const vuint4*)(Ap + (size_t)(m0 + r) * 1024 + kk);
      } else if (V == 6) {
        if (r < 64) v = *(const vuint4*)(Ap + (size_t)r * 1024 + kk);
        else v = vuint4{0u, 0u, 0u, 0u};
      } else { // V7: even boundary states from Abnd
        if (r < 32) {
          int b = r & 1, k2 = r >> 1;
          v = *(const vuint4*)(Ap + (size_t)(b * 32 + 2 * k2) * 1024 + kk);
        } else v = vuint4{0u, 0u, 0u, 0u};
      }
      *(vuint4*)(&lA[(((r >> 4) * 4 + cq) * 16 + (r & 15)) * 8]) = v;

      int n = n0 + r;
      vuint4 w;
      if (V == 0) {
        w = *(const vuint4*)(a.B + (size_t)n * 512 + kk);
      } else if (V == 1) {
        int kh = kk >> 7, sp = kk & 127;
        w = *(const vuint4*)(a.B + (size_t)(cb * 512 + n) * 49152 + kh * 1024 + cj * 128 + sp);
      } else if (V == 2) {
        int tau = kk >> 9, p = kk & 511;
        w = *(const vuint4*)(a.B + (size_t)tau * 524288 + (size_t)n * 1024 + p);
      } else if (V == 3) {
        int jn = n >> 9, o = n & 511;
        w = *(const vuint4*)(a.B + (size_t)(jn + 1) * 524288 + (size_t)o * 1024 + kk);
      } else if (V == 5) {
        w = *(const vuint4*)(a.B + (size_t)n * 1024 + kk);
      } else { // V6/V7: rows of S32 = [Top32 ; Top31]
        const u16* src = (n < 512)
            ? (a.B + (size_t)32 * 524288 + (size_t)n * 1024 + kk)
            : (a.B + (size_t)31 * 524288 + (size_t)(n - 512) * 1024 + kk);
        w = *(const vuint4*)src;
      }
      *(vuint4*)(&lB[(((r >> 4) * 4 + cq) * 16 + (r & 15)) * 8]) = w;
    }
    __syncthreads();
    vshort8 af[4], bf_[4];
#pragma unroll
    for (int s = 0; s < 4; s++) {
      af[s]  = *(const vshort8*)&lA[(((wr * 4 + s) * 4 + (lane >> 4)) * 16 + (lane & 15)) * 8];
      bf_[s] = *(const vshort8*)&lB[(((wc * 4 + s) * 4 + (lane >> 4)) * 16 + (lane & 15)) * 8];
    }
#pragma unroll
    for (int i = 0; i < 4; i++)
#pragma unroll
      for (int j = 0; j < 4; j++)
        acc[i][j] = __builtin_amdgcn_mfma_f32_16x16x32_bf16(af[i], bf_[j], acc[i][j], 0, 0, 0);
    __syncthreads();
  }

  // epilogue
#pragma unroll
  for (int i = 0; i < 4; i++) {
    int em = m0 + wr * 64 + i * 16 + ((lane >> 4) << 2);
#pragma unroll
    for (int j = 0; j < 4; j++) {
      int n = n0 + wc * 64 + j * 16 + (lane & 15);
      f32x4 v = acc[i][j];
      if (V == 0) {
        int b = em >> 10, s = em & 1023;
        if (n < 24576) {
          int kh = n >> 9, o = n & 511;
          vshort4 pk = { (short)f2b(v[0]), (short)f2b(v[1]), (short)f2b(v[2]), (short)f2b(v[3]) };
          *(vshort4*)(&a.A2T[(size_t)(b * 512 + o) * 49152 + (size_t)kh * 1024 + s]) = pk;
        } else {
          int jj = (n - 24576) >> 9, o = n & 511;
#pragma unroll
          for (int t = 0; t < 4; t++)
            a.Au[((size_t)(b * 3 + jj) * 1024 + (s + t)) * 512 + o] = f2b(v[t]);
        }
      } else if (V == 1) {
        float* C = a.Cf + (size_t)(cb * 16 + chh * 8 + cj) * 524288;
#pragma unroll
        for (int t = 0; t < 4; t++) C[(size_t)(em + t) * 512 + n] = v[t];
      } else if (V == 2) {
        float* C = a.Cf + (size_t)bz * 1048576;
#pragma unroll
        for (int t = 0; t < 4; t++) C[(size_t)(em + t) * 512 + n] = v[t];
      } else if (V == 3) {
        int jj = n >> 9, oo = n & 511;
#pragma unroll
        for (int t = 0; t < 4; t++) {
          int m = em + t;
          if (m < a.M) {
            int b = m >> 5, c = m & 31;
            float zv = a.zf[(size_t)(jj * 64 + b * 32 + c) * 512 + oo];
            a.out[(size_t)b * 524288 + (size_t)(c * 32 + jj) * 512 + oo] = v[t] + zv;
          }
        }
      } else if (V == 5) {
        u16* C = a.Cb + (size_t)bz * 524288;
#pragma unroll
        for (int t = 0; t < 4; t++) C[(size_t)(em + t) * 1024 + n] = f2b(v[t]);
      } else if (V == 6) {
        // u_c = acc + w_{c+1}; rows m=(c<<1)|b valid for m<62
        int jrow = (n < 512) ? 31 : 30, oo = n & 511;
#pragma unroll
        for (int t = 0; t < 4; t++) {
          int m = em + t;
          if (m < 62) {
            int b = m & 1, c = m >> 1;
            a.Cf[(size_t)m * 1024 + n] =
                v[t] + a.zf[(size_t)(jrow * 64 + b * 32 + (c + 1)) * 512 + oo];
          }
        }
      } else { // V7: odd states
        int jrow = (n < 512) ? 31 : 30, oo = n & 511;
#pragma unroll
        for (int t = 0; t < 4; t++) {
          int m = em + t;
          if (m < 32) {
            int b = m & 1, k2 = m >> 1;
            float val = v[t] + a.zf[(size_t)(jrow * 64 + b * 32 + 2 * k2) * 512 + oo];
            a.Cb[(size_t)(b * 32 + 2 * k2 + 1) * 1024 + n] = f2b(val);
          }
        }
      }
    }
  }
}

// ---------------------------------------------------------------------------
// prep / glue kernels
// ---------------------------------------------------------------------------
__global__ void k_prep_X(const float* __restrict__ u, u16* __restrict__ X, int n) {
  int i = blockIdx.x * 256 + threadIdx.x;
  if (i < n) X[i] = f2b(u[i]);
}

__global__ void k_prep_phis(const float* __restrict__ phi, const float* __restrict__ sigma,
                            float* __restrict__ phis) {
  int i = blockIdx.x * 256 + threadIdx.x;
  if (i >= 1024 * 48) return;
  int tau = i / 48, kf = i % 48, k = (kf >= 24) ? kf - 24 : kf;
  float v = phi[tau * 24 + k] * powf(sigma[k], 0.25f);
  if (kf >= 24 && (tau & 1)) v = -v;
  phis[i] = v;
}

__global__ void k_prep_W1(const float* __restrict__ Mp, const float* __restrict__ Mm,
                          const float* __restrict__ Mu, u16* __restrict__ W1) {
  int i = blockIdx.x * 256 + threadIdx.x;
  if (i >= 13369344) return;
  float v;
  if (i < 6291456) v = Mp[i];
  else if (i < 12582912) v = Mm[i - 6291456];
  else v = Mu[i - 12582912];
  W1[i] = f2b(v);
}

// Wtoep[d][t'][kh*128+s'] = phis[(d*128+t'-s')*48 + kh] (0 if tau<0)
__global__ void k_prep_Wtoep(const float* __restrict__ phis, u16* __restrict__ W) {
  int i = blockIdx.x * 256 + threadIdx.x;
  if (i >= 6291456) return;
  int kap = i % 6144, row = i / 6144;
  int tp = row & 127, d = row >> 7;
  int kh = kap >> 7, sp = kap & 127;
  int tau = d * 128 + tp - sp;
  W[i] = (tau >= 0 && tau < 1024) ? f2b(phis[tau * 48 + kh]) : (u16)0;
}

// Top[0]=[I|0], Top[1]=[M1|M2]
__global__ void k_initTop(const float* __restrict__ my, u16* __restrict__ Top) {
  int i = blockIdx.x * 256 + threadIdx.x;
  if (i >= 1048576) return;
  int mat = i >> 19, rem = i & 524287, o = rem >> 10, k = rem & 1023;
  u16 v;
  if (mat == 0) v = (k == o) ? (u16)0x3F80 : (u16)0;
  else v = (k < 512) ? f2b(my[o * 512 + k]) : f2b(my[262144 + o * 512 + (k - 512)]);
  Top[i] = v;
}

// STc[n][k] = S^c[k][n];  S^c = [Top[c]; Top[c-1]]  (tiled transpose)
__global__ __launch_bounds__(256) void k_transT(const u16* __restrict__ Top,
                                                u16* __restrict__ STc, int c) {
  __shared__ u16 tile[64][72];
  int tx = blockIdx.x, ty = blockIdx.y;  // n-tile, k-tile
  int tid = threadIdx.x;
  int r = tid >> 2, seg = tid & 3;
  int k = ty * 64 + r;
  const u16* src = (k < 512) ? Top + (size_t)c * 524288 + (size_t)k * 1024 + tx * 64
                             : Top + (size_t)(c - 1) * 524288 + (size_t)(k - 512) * 1024 + tx * 64;
  *(vuint4*)&tile[r][seg * 16]     = *(const vuint4*)(src + seg * 16);
  *(vuint4*)&tile[r][seg * 16 + 8] = *(const vuint4*)(src + seg * 16 + 8);
  __syncthreads();
  int n = tx * 64 + r;
  u16 tmp[16];
#pragma unroll
  for (int j = 0; j < 16; j++) tmp[j] = tile[seg * 16 + j][r];
  *(vuint4*)&STc[(size_t)n * 1024 + ty * 64 + seg * 16]     = *(vuint4*)&tmp[0];
  *(vuint4*)&STc[(size_t)n * 1024 + ty * 64 + seg * 16 + 8] = *(vuint4*)&tmp[8];
}

// ybf[b,t,o] = sum_j Au[b,j,t-j,o] + (t>=2 ? valid conv partials at t-2 : 0)
__global__ void k_combine(const float* __restrict__ parts, const u16* __restrict__ Au,
                          u16* __restrict__ ybf) {
  int i = blockIdx.x * 256 + threadIdx.x;
  if (i >= 1048576) return;
  int b = i >> 19, rest = i & 524287, t = rest >> 9, o = rest & 511;
  float y = 0.f;
#pragma unroll
  for (int j = 0; j < 3; j++)
    if (t >= j) y += b2f(Au[((size_t)(b * 3 + j) * 1024 + (t - j)) * 512 + o]);
  if (t >= 2) {
    int tp = t - 2, bmv = tp >> 7;
    size_t e = (size_t)tp * 512 + o;
    for (int j = 0; j <= bmv; ++j)
      y += parts[(size_t)(b * 16 + j) * 524288 + e] +
           parts[(size_t)(b * 16 + 8 + j) * 524288 + e];
  }
  ybf[i] = f2b(y);
}

__global__ void k_zreduce(const float* __restrict__ zp, float* __restrict__ z) {
  int i = blockIdx.x * 256 + threadIdx.x;
  if (i >= 1048576) return;
  float s = 0.f;
#pragma unroll
  for (int j = 0; j < 8; j++) s += zp[(size_t)j * 1048576 + i];
  z[i] = s;
}

// Wm[(c<<1)|b][n] = bf16(w_c(b)[n]) from zf rows 31 (n<512) / 30 (n>=512)
__global__ void k_wm(const float* __restrict__ zf, u16* __restrict__ Wm) {
  int i = blockIdx.x * 256 + threadIdx.x;
  if (i >= 65536) return;
  int row = i >> 10, n = i & 1023;
  int b = row & 1, c = row >> 1;
  int jrow = (n < 512) ? 31 : 30, oo = n & 511;
  Wm[i] = f2b(zf[(size_t)(jrow * 64 + b * 32 + c) * 512 + oo]);
}

// even chain step k: E_{k+1} = S64 E_k + u_{2k}; emit Abnd row (b*32+2k+2)
__global__ __launch_bounds__(256) void k_bnd2(const u16* __restrict__ Top,
                                              const float* __restrict__ ubuf,
                                              float* __restrict__ bnd,
                                              u16* __restrict__ Abnd, int k) {
  __shared__ float st[2048];
  int tid = threadIdx.x;
  const float* s0 = bnd + (size_t)k * 2048;
  for (int j = tid; j < 2048; j += 256) st[j] = s0[j];
  __syncthreads();
  int q4 = blockIdx.x * 256 + tid;  // [0,8192)
  int q = q4 >> 2, quarter = q4 & 3;
  int b = q >> 10, kk = q & 1023;
  const u16* row = (kk < 512) ? Top + (size_t)64 * 524288 + (size_t)kk * 1024
                              : Top + (size_t)63 * 524288 + (size_t)(kk - 512) * 1024;
  const float* stb = st + b * 1024 + quarter * 256;
  const u16* rp = row + quarter * 256;
  float sum = 0.f;
  for (int t = 0; t < 32; ++t) {
    vuint4 v = *(const vuint4*)(rp + t * 8);
    const unsigned int* vu = (const unsigned int*)&v;
#pragma unroll
    for (int e = 0; e < 4; ++e) {
      unsigned int pw = vu[e];
      float lo = __builtin_bit_cast(float, (pw & 0xffffu) << 16);
      float hi = __builtin_bit_cast(float, pw & 0xffff0000u);
      sum += lo * stb[t * 8 + e * 2] + hi * stb[t * 8 + e * 2 + 1];
    }
  }
  sum += __shfl_xor(sum, 1);
  sum += __shfl_xor(sum, 2);
  if (quarter == 0) {
    float s = sum + ubuf[(size_t)(4 * k + b) * 1024 + kk];
    bnd[(size_t)(k + 1) * 2048 + b * 1024 + kk] = s;
    Abnd[(size_t)(b * 32 + 2 * k + 2) * 1024 + kk] = f2b(s);
  }
}

// ---------------------------------------------------------------------------
extern "C" void kernel_launch(void* const* d_in, const int* in_sizes, int n_in,
                              void* d_out, int out_size, void* d_ws, size_t ws_size,
                              hipStream_t stream) {
  const float* u     = (const float*)d_in[0];
  const float* Mu    = (const float*)d_in[1];
  const float* Mp    = (const float*)d_in[2];
  const float* Mm    = (const float*)d_in[3];
  const float* my    = (const float*)d_in[4];
  const float* sigma = (const float*)d_in[5];
  const float* phi   = (const float*)d_in[6];
  float* out = (float*)d_out;

  char* ws = (char*)d_ws;
  size_t off = 0;
  auto alc = [&](size_t b) { size_t p = off; off = (off + b + 255) & ~(size_t)255; return p; };
  u16*  X     = (u16*)(ws + alc(2097152));
  u16*  Wtoep = (u16*)(ws + alc(12582912));    // 8 d x 128 x 6144
  u16*  A2T   = (u16*)(ws + alc(100663296));   // (b,o)[48 kh][1024 s]
  u16*  Au    = (u16*)(ws + alc(6291456));
  u16*  W1    = (u16*)(ws + alc(26738688));    // 26112x512; partsBig spans W1+tail
  char* ptail = ws + alc(40370176); (void)ptail; // W1(26738688)+tail = 64 MiB exactly
  float* phis = (float*)(ws + alc(196608));
  float* bnd  = (float*)(ws + alc(131072));    // 16 even states x 2048 f32
  u16*  Abnd  = (u16*)(ws + alc(131072));      // 64 x 1024 bf16 boundary states
  u16*  Wm    = (u16*)(ws + alc(131072));      // 64 x 1024 bf16 w_c
  float* ubuf = (float*)(ws + alc(262144));    // 64 x 1024 f32 u_c
  if (off > ws_size) return;
  // lifetime-disjoint aliases:
  float* partsBig = (float*)W1;                // 32 conv slots x 2 MB (after GEMM1)
  float* zparts   = partsBig;                  // 8 zgemm slots x 4 MB (after combine)
  u16*  ybf = A2T;                             // 2 MB (after conv)
  float* zf = (float*)((char*)A2T + (4 << 20));
  u16*  Top = (u16*)((char*)A2T + (size_t)(8 << 20));   // 65 x 1 MB (after conv)
  u16*  STc = (u16*)((char*)A2T + (size_t)(76 << 20));  // 2 MB scratch

  // prep
  k_prep_X<<<dim3(4096), 256, 0, stream>>>(u, X, 1048576);
  k_prep_phis<<<dim3(192), 256, 0, stream>>>(phi, sigma, phis);
  k_prep_W1<<<dim3(52224), 256, 0, stream>>>(Mp, Mm, Mu, W1);
  k_prep_Wtoep<<<dim3(24576), 256, 0, stream>>>(phis, Wtoep);

  // GEMM1: projections (spectral plus/minus + ar_u)
  {
    GB g{}; g.A = X; g.B = W1; g.A2T = A2T; g.Au = Au; g.M = 2048; g.N = 26112;
    g2<0><<<dim3(204, 16, 1), 256, 0, stream>>>(g);
  }
  // CONV: active-only triangular grid, splitK over (ch,cb)
  {
    GB g{}; g.A = Wtoep; g.B = A2T; g.Cf = partsBig; g.M = 1024; g.N = 512;
    g2<1><<<dim3(36, 4, 4), 256, 0, stream>>>(g);
  }
  k_combine<<<dim3(4096), 256, 0, stream>>>(partsBig, Au, ybf);

  // companion-power stack Top[0..32], then Top[63],Top[64] (= S32^2 halves)
  k_initTop<<<dim3(4096), 256, 0, stream>>>(my, Top);
  {
    const int cs[5] = {1, 2, 4, 8, 16};
    for (int li = 0; li < 5; ++li) {
      int c = cs[li];
      k_transT<<<dim3(16, 16), 256, 0, stream>>>(Top, STc, c);
      GB s{}; s.A = Top + 524288; s.B = STc; s.Cb = Top + (size_t)(c + 1) * 524288;
      s.M = 512; s.N = 1024;
      g2<5><<<dim3(8, 4, c), 256, 0, stream>>>(s);
    }
    // Top[63] = Top[31] * S^32, Top[64] = Top[32] * S^32
    k_transT<<<dim3(16, 16), 256, 0, stream>>>(Top, STc, 32);
    GB s{}; s.A = Top + (size_t)31 * 524288; s.B = STc;
    s.Cb = Top + (size_t)63 * 524288; s.M = 512; s.N = 1024;
    g2<5><<<dim3(8, 4, 2), 256, 0, stream>>>(s);
  }

  // within-chunk solve: z = Tri(H) y, splitK over tau-blocks
  {
    GB g{}; g.A = ybf; g.B = Top; g.Cf = zparts; g.M = 2048; g.N = 512;
    g2<2><<<dim3(4, 16, 8), 256, 0, stream>>>(g);
  }
  k_zreduce<<<dim3(4096), 256, 0, stream>>>(zparts, zf);

  // boundary chain: u_c precompute, 15 even steps, batched odd fill
  k_wm<<<dim3(256), 256, 0, stream>>>(zf, Wm);
  {
    GB g{}; g.A = Wm; g.B = Top; g.Cf = ubuf; g.zf = zf; g.M = 64; g.N = 1024;
    g2<6><<<dim3(8, 1, 1), 256, 0, stream>>>(g);
  }
  hipMemsetAsync(bnd, 0, 8192, stream);
  hipMemsetAsync(Abnd, 0, 131072, stream);
  for (int k = 0; k < 15; ++k)
    k_bnd2<<<dim3(32), 256, 0, stream>>>(Top, ubuf, bnd, Abnd, k);
  {
    GB g{}; g.A = Abnd; g.B = Top; g.Cb = Abnd; g.zf = zf; g.M = 32; g.N = 1024;
    g2<7><<<dim3(8, 1, 1), 256, 0, stream>>>(g);
  }

  // fixup: out = z + [H_{j+1}|G_j] @ Abnd
  {
    GB g{}; g.A = Abnd; g.B = Top; g.zf = zf; g.out = out; g.M = 64; g.N = 16384;
    g2<3><<<dim3(128, 1, 1), 256, 0, stream>>>(g);
  }
}